// Round 1
// baseline (732.712 us; speedup 1.0000x reference)
//
#include <hip/hip_runtime.h>
#include <hip/hip_bf16.h>
#include <cstdint>
#include <cstddef>

// Problem constants
#define Bsz 8192
#define Hdim 2048
#define Kdim 4096   // EFF
#define Nall 4096   // 2*H (cand cols 0..2047, gate cols 2048..4095)

// GEMM tiling (m97 structure)
#define BM 128
#define BN 128
#define BK 32

typedef __attribute__((ext_vector_type(8))) short short8;   // 8 bf16 (4 VGPRs)
typedef __attribute__((ext_vector_type(4))) float floatx4;  // 4 fp32 acc

// fp32 -> bf16 bits, round-to-nearest-even (inputs finite; no NaN path needed)
__device__ __forceinline__ short f2bf(float f) {
    unsigned u = __float_as_uint(f);
    unsigned r = (u + 0x7fffu + ((u >> 16) & 1u)) >> 16;
    return (short)(r & 0xffffu);
}

// async global->LDS, 16B per lane; LDS dest = wave-uniform base + lane*16
__device__ __forceinline__ void g2l16(const void* g, void* l) {
    __builtin_amdgcn_global_load_lds(
        (const __attribute__((address_space(1))) unsigned int*)g,
        (__attribute__((address_space(3))) unsigned int*)l,
        16, 0, 0);
}

// ---------------------------------------------------------------------------
// Kernel 1: combined weight build + transpose.
// Wt[n][k] (bf16) = n<2048 ? Wc[k][n] + (k>=2048)*Uc[k-2048][n]
//                          : Wg[k][n-2048] + (k>=2048)*Ug[k-2048][n-2048]
// 32x32 LDS-tiled transpose; tile boundaries align with the 2048 splits.
// ---------------------------------------------------------------------------
__global__ __launch_bounds__(256) void build_wt(
    const float* __restrict__ Wc, const float* __restrict__ Uc,
    const float* __restrict__ Wg, const float* __restrict__ Ug,
    short* __restrict__ Wt)
{
    __shared__ float tile[32][33];
    const int nt = blockIdx.x * 32;   // n tile base
    const int kt = blockIdx.y * 32;   // k tile base
    const int tx = threadIdx.x & 31;
    const int ty = threadIdx.x >> 5;  // 0..7

    const bool isGate = (nt >= Hdim);
    const float* W = isGate ? Wg : Wc;
    const float* U = isGate ? Ug : Uc;
    const int ncol = isGate ? (nt - Hdim) : nt;

#pragma unroll
    for (int r = 0; r < 32; r += 8) {
        int k = kt + ty + r;
        float v = W[(size_t)k * Hdim + ncol + tx];
        if (k >= Hdim) v += U[(size_t)(k - Hdim) * Hdim + ncol + tx];
        tile[ty + r][tx] = v;
    }
    __syncthreads();
#pragma unroll
    for (int r = 0; r < 32; r += 8) {
        int n = nt + ty + r;
        int k = kt + tx;
        Wt[(size_t)n * Kdim + k] = f2bf(tile[tx][ty + r]);
    }
}

// ---------------------------------------------------------------------------
// Kernel 2: Acat[b][k] (bf16) = k<2048 ? x_t[b][k] : state[b][k-2048]
// Each thread: 8 elems, float4 x2 in, short8 (16B) out.
// ---------------------------------------------------------------------------
__global__ __launch_bounds__(256) void build_acat(
    const float* __restrict__ x, const float* __restrict__ st,
    short* __restrict__ A)
{
    int idx = blockIdx.x * 256 + threadIdx.x;   // one per 8 elems
    int row = idx >> 9;                          // 4096/8 = 512 per row
    int c = (idx & 511) * 8;                     // wave-uniform branch (512%512)
    const float* src = (c < Hdim) ? (x + (size_t)row * Hdim + c)
                                  : (st + (size_t)row * Hdim + (c - Hdim));
    float4 v0 = ((const float4*)src)[0];
    float4 v1 = ((const float4*)src)[1];
    short8 o;
    o[0] = f2bf(v0.x); o[1] = f2bf(v0.y); o[2] = f2bf(v0.z); o[3] = f2bf(v0.w);
    o[4] = f2bf(v1.x); o[5] = f2bf(v1.y); o[6] = f2bf(v1.z); o[7] = f2bf(v1.w);
    *(short8*)(A + (size_t)row * Kdim + c) = o;
}

// ---------------------------------------------------------------------------
// Kernel 3: GEMM  pre[M][N] = Acat[M][K] * Wt[N][K]^T   (m97 structure)
// 128x128 tile, BK=32, 4 waves in 2x2, each wave 4x4 accs of 16x16x32 MFMA.
// global_load_lds width=16 staging, single LDS buffer, 2-barrier K-loop.
// ---------------------------------------------------------------------------
__global__ void gemm_bt(
    const short* __restrict__ A,   // [M][K] bf16 bits
    const short* __restrict__ Bt,  // [N][K] bf16 bits
    float* __restrict__ C,         // [M][N] fp32
    int M, int N, int K)
{
    __shared__ __attribute__((aligned(16))) short sA[BM * BK]; // [128][32]
    __shared__ __attribute__((aligned(16))) short sB[BN * BK]; // [128][32]

    const int tid  = threadIdx.x;
    const int lane = tid & 63;
    const int wave = tid >> 6;    // 0..3
    const int wm = wave >> 1;     // 0..1
    const int wn = wave & 1;

    const int m0 = blockIdx.y * BM;
    const int n0 = blockIdx.x * BN;

    floatx4 acc[4][4];
#pragma unroll
    for (int i = 0; i < 4; ++i)
#pragma unroll
        for (int j = 0; j < 4; ++j) {
            floatx4 z = {0.f, 0.f, 0.f, 0.f};
            acc[i][j] = z;
        }

    // staging: chunk c = tid + 256*i covers row c>>2, col elems (c&3)*8
    const int r0 = tid >> 2;
    const int c0 = (tid & 3) * 8;
    const short* Ag0 = A  + (size_t)(m0 + r0)      * K + c0;
    const short* Ag1 = A  + (size_t)(m0 + 64 + r0) * K + c0;
    const short* Bg0 = Bt + (size_t)(n0 + r0)      * K + c0;
    const short* Bg1 = Bt + (size_t)(n0 + 64 + r0) * K + c0;

    // wave-uniform LDS bases (chunk base = wave*64 + 256*i, *8 shorts = *16B)
    short* sA0 = sA + (wave * 64 +   0) * 8;
    short* sA1 = sA + (wave * 64 + 256) * 8;
    short* sB0 = sB + (wave * 64 +   0) * 8;
    short* sB1 = sB + (wave * 64 + 256) * 8;

    // fragment read addresses
    const int fr = lane & 15;          // m (or n) within 16
    const int fk = (lane >> 4) * 8;    // k base for this quad
    const short* sAf = sA + (wm * 64 + fr) * BK + fk;
    const short* sBf = sB + (wn * 64 + fr) * BK + fk;

    for (int k0 = 0; k0 < K; k0 += BK) {
        __syncthreads();               // prior compute done before overwrite
        g2l16(Ag0, sA0); g2l16(Ag1, sA1);
        g2l16(Bg0, sB0); g2l16(Bg1, sB1);
        Ag0 += BK; Ag1 += BK; Bg0 += BK; Bg1 += BK;
        __syncthreads();               // drains vmcnt(0): LDS tiles valid

        short8 a[4], b[4];
#pragma unroll
        for (int i = 0; i < 4; ++i) a[i] = *(const short8*)(sAf + i * 16 * BK);
#pragma unroll
        for (int j = 0; j < 4; ++j) b[j] = *(const short8*)(sBf + j * 16 * BK);
#pragma unroll
        for (int i = 0; i < 4; ++i)
#pragma unroll
            for (int j = 0; j < 4; ++j)
                acc[i][j] = __builtin_amdgcn_mfma_f32_16x16x32_bf16(
                    a[i], b[j], acc[i][j], 0, 0, 0);
    }

    // C/D layout: col = lane&15, row = (lane>>4)*4 + reg   [measured m89/m91]
    const int cn = lane & 15;
    const int cr = (lane >> 4) * 4;
#pragma unroll
    for (int i = 0; i < 4; ++i) {
#pragma unroll
        for (int j = 0; j < 4; ++j) {
            int row = m0 + wm * 64 + i * 16 + cr;
            int col = n0 + wn * 64 + j * 16 + cn;
            float* Cp = C + (size_t)row * N + col;
#pragma unroll
            for (int r = 0; r < 4; ++r) Cp[(size_t)r * N] = acc[i][j][r];
        }
    }
}

// ---------------------------------------------------------------------------
// Kernel 4: epilogue. One block per batch row.
// cand=tanh(pc+bc), gate=sigmoid(pg+bg), alpha=exp(-exp(-log_step)),
// h=alpha*state+(1-alpha)*gate*cand, then LayerNorm(h)*gamma+beta.
// ---------------------------------------------------------------------------
__global__ __launch_bounds__(256) void epilogue_k(
    const float* __restrict__ pre,   // [B][4096]: cand_pre | gate_pre
    const float* __restrict__ st,    // [B][2048]
    const float* __restrict__ bc, const float* __restrict__ bg,
    const float* __restrict__ lstep, const float* __restrict__ gam,
    const float* __restrict__ bet, float* __restrict__ out)
{
    const int b = blockIdx.x;
    const int t = threadIdx.x;
    const int n0 = t * 8;
    const float* pc = pre + (size_t)b * Nall + n0;
    const float* pg = pc + Hdim;
    const float* sr = st + (size_t)b * Hdim + n0;

    float h[8];
    float sum = 0.f, ss = 0.f;
#pragma unroll
    for (int i = 0; i < 8; ++i) {
        int n = n0 + i;
        float cand = tanhf(pc[i] + bc[n]);
        float gx = pg[i] + bg[n];
        float gate = 1.f / (1.f + __expf(-gx));
        float alpha = __expf(-__expf(-lstep[n]));
        float hv = alpha * sr[i] + (1.f - alpha) * gate * cand;
        h[i] = hv;
        sum += hv;
        ss += hv * hv;
    }

    // wave reduce (64 lanes) then cross-wave via LDS
#pragma unroll
    for (int off = 32; off > 0; off >>= 1) {
        sum += __shfl_down(sum, off);
        ss  += __shfl_down(ss, off);
    }
    __shared__ float red[2][4];
    if ((t & 63) == 0) { red[0][t >> 6] = sum; red[1][t >> 6] = ss; }
    __syncthreads();
    sum = red[0][0] + red[0][1] + red[0][2] + red[0][3];
    ss  = red[1][0] + red[1][1] + red[1][2] + red[1][3];

    const float inv = 1.f / (float)Hdim;
    float mu = sum * inv;
    float var = ss * inv - mu * mu;
    float rs = rsqrtf(var + 1e-5f);

    float* op = out + (size_t)b * Hdim + n0;
#pragma unroll
    for (int i = 0; i < 8; ++i) {
        int n = n0 + i;
        op[i] = (h[i] - mu) * rs * gam[n] + bet[n];
    }
}

// ---------------------------------------------------------------------------
extern "C" void kernel_launch(void* const* d_in, const int* in_sizes, int n_in,
                              void* d_out, int out_size, void* d_ws, size_t ws_size,
                              hipStream_t stream)
{
    const float* x_t   = (const float*)d_in[0];
    const float* state = (const float*)d_in[1];
    const float* Wc    = (const float*)d_in[2];
    const float* Uc    = (const float*)d_in[3];
    const float* bc    = (const float*)d_in[4];
    const float* Wg    = (const float*)d_in[5];
    const float* Ug    = (const float*)d_in[6];
    const float* bg    = (const float*)d_in[7];
    const float* lstep = (const float*)d_in[8];
    const float* gam   = (const float*)d_in[9];
    const float* bet   = (const float*)d_in[10];
    float* out = (float*)d_out;

    // workspace layout: Wt (32MB) | Acat (64MB) | pre (128MB) = 224MB
    char* ws = (char*)d_ws;
    short* Wt   = (short*)ws;
    short* Acat = (short*)(ws + (size_t)32 * 1024 * 1024);
    float* pre  = (float*)(ws + (size_t)96 * 1024 * 1024);

    build_wt<<<dim3(Nall / 32, Kdim / 32), 256, 0, stream>>>(Wc, Uc, Wg, Ug, Wt);
    build_acat<<<(Bsz * (Kdim / 8)) / 256, 256, 0, stream>>>(x_t, state, Acat);
    gemm_bt<<<dim3(Nall / BN, Bsz / BM), 256, 0, stream>>>(Acat, Wt, pre,
                                                           Bsz, Nall, Kdim);
    epilogue_k<<<Bsz, 256, 0, stream>>>(pre, state, bc, bg, lstep, gam, bet, out);
}